// Round 14
// baseline (195.356 us; speedup 1.0000x reference)
//
#include <hip/hip_runtime.h>
#include <hip/hip_bf16.h>

#define KT 576   // CIN*9, GEMM k-order k' = (p*3+q)*64 + c

typedef __attribute__((ext_vector_type(8))) short  short8;
typedef __attribute__((ext_vector_type(4))) float  f32x4;

#define VMCNT(n) asm volatile("s_waitcnt vmcnt(" #n ")" ::: "memory")
#define SB() __builtin_amdgcn_sched_barrier(0)

__device__ __forceinline__ unsigned short f2bf(float f) {
  union { float f; unsigned int u; } v; v.f = f;
  return (unsigned short)((v.u + 0x7FFFu + ((v.u >> 16) & 1u)) >> 16);  // RNE
}

// ---------------------------------------------------------------------------
// Pre-pass: xC2 bf16, layout [hp 34][wp 34][bb 8][cs 8][bl 16][cl 8].
// ---------------------------------------------------------------------------
__global__ __launch_bounds__(256) void xC2_kernel(const float* __restrict__ x,
                                                  unsigned short* __restrict__ xC2) {
  const int hp = blockIdx.x, bb = blockIdx.y, t = threadIdx.x;
  __shared__ unsigned short tile[32 * 1024];   // [w 32][cs 8][bl 16][cl 8]
  const bool interior = (hp >= 1 && hp <= 32);
  if (interior) {
#pragma unroll 4
    for (int i = 0; i < 32; ++i) {
      const int row = i * 32 + (t >> 3);       // = bl*64 + c
      const int bl = row >> 6, c = row & 63;
      const int k = t & 7;
      const float4 v = *(const float4*)(x + ((size_t)(bb * 16 + bl) * 64 + c) * 1024 +
                                        (hp - 1) * 32 + k * 4);
      const int base = (k * 4) * 1024 + (c >> 3) * 128 + bl * 8 + (c & 7);
      tile[base]        = f2bf(v.x);
      tile[base + 1024] = f2bf(v.y);
      tile[base + 2048] = f2bf(v.z);
      tile[base + 3072] = f2bf(v.w);
    }
  }
  __syncthreads();
  unsigned short* dst = xC2 + (size_t)hp * 278528 + (size_t)bb * 1024;
  const uint4 z = make_uint4(0u, 0u, 0u, 0u);
  for (int idx = t; idx < 34 * 128; idx += 256) {
    const int wp = idx >> 7, s = idx & 127;
    uint4 v = z;
    if (interior && wp >= 1 && wp <= 32) v = *(const uint4*)&tile[(wp - 1) * 1024 + s * 8];
    *(uint4*)(dst + (size_t)wp * 8192 + s * 8) = v;
  }
}

// ---------------------------------------------------------------------------
// Main: 256 blocks = (h 32) x (wq 8); 512 threads = 8 waves = (b-tile 4) x
// (d-half 2) -> 2 waves/SIMD (TLP hides VMEM waits; the 4-wave configs had
// 1 wave/SIMD = dead SIMD on every vmcnt stall). 4 chained mini-GEMMs
// (w = wq*4+j), full 64-d W tile double-buffered in LDS (148 KB), staged in
// 9-load half-batches via one wreg[9]; counted-vmcnt ledger; XOR-swizzled
// slots; acc held across j -> float4-over-w epilogue.
// ---------------------------------------------------------------------------
__global__ __launch_bounds__(512, 1) void lc_main(const float* __restrict__ Wt,
                                                  const float* __restrict__ bias,
                                                  const unsigned short* __restrict__ xC2,
                                                  float* __restrict__ out) {
  __shared__ unsigned short Wl[2][64 * KT];   // 2 x 73728 B
  __shared__ float blds[256];                 // [j 4][d 64]

  const int bid = (int)blockIdx.x;
  const int swz = (bid & 7) * 32 + (bid >> 3);    // 32-block chunks per XCD
  const int h = swz >> 3, wq = swz & 7;
  const int t = threadIdx.x, lane = t & 63, wv = t >> 6;
  const int bw = wv & 3, dh = wv >> 2;            // b-tile, d-half of this wave
  const int l15 = lane & 15, lg = lane >> 4;

  if (t < 256)
    blds[t] = bias[(t & 63) * 1024 + h * 32 + wq * 4 + (t >> 6)];

  const unsigned short* xA = xC2 + (size_t)bw * 2048 + lg * 128 + l15 * 8;
  const int x7 = l15 & 7;
  const int wrow0 = (dh * 32 + l15) * KT;
  const int wrow1 = (dh * 32 + 16 + l15) * KT;

  f32x4 acc[4][2][2];
#pragma unroll
  for (int j = 0; j < 4; ++j)
#pragma unroll
    for (int bt = 0; bt < 2; ++bt)
#pragma unroll
      for (int dt = 0; dt < 2; ++dt) acc[j][bt][dt] = (f32x4){0.f, 0.f, 0.f, 0.f};

  short8 As0[3][3], As1[3][3];   // A slots [(j*6+g)%3][s]
  float4 wreg[9];                // one W half-batch (32 d rows), reused

#define ISSUE_W9(jj, hs)                                                      \
  {                                                                           \
    const float* ws = Wt + (size_t)(h * 32 + wq * 4 + (jj)) * (64 * KT) +     \
                      (size_t)(hs) * (32 * KT);                               \
    _Pragma("unroll")                                                         \
    for (int i = 0; i < 9; ++i) {                                             \
      const float4* p = (const float4*)ws + (i * 512 + t);                    \
      asm volatile("global_load_dwordx4 %0, %1, off" : "=v"(wreg[i]) : "v"(p)); \
    }                                                                         \
  }

#define ISSUE_A(K)                                                            \
  {                                                                           \
    _Pragma("unroll")                                                         \
    for (int s = 0; s < 3; ++s) {                                             \
      const int step = ((K) % 6) * 3 + s;                                     \
      const int pq = step >> 1, p = pq / 3, q = pq - p * 3;                   \
      const size_t off = (size_t)(h + p) * 278528 +                           \
                         (size_t)(wq * 4 + (K) / 6 + q) * 8192 + (step & 1) * 512; \
      const short8* p0 = (const short8*)(xA + off);                           \
      const short8* p1 = (const short8*)(xA + off + 1024);                    \
      asm volatile("global_load_dwordx4 %0, %1, off" : "=v"(As0[(K) % 3][s]) : "v"(p0)); \
      asm volatile("global_load_dwordx4 %0, %1, off" : "=v"(As1[(K) % 3][s]) : "v"(p1)); \
    }                                                                         \
  }

#define SCATTER9(buf, hs)                                                     \
  {                                                                           \
    _Pragma("unroll")                                                         \
    for (int i = 0; i < 9; ++i) {                                             \
      const int f = (i * 512 + t) * 4;                                        \
      const int dl = (((unsigned)(f >> 6)) * 7282u) >> 16;                    \
      int kn = f - dl * 576;                                                  \
      int c = ((unsigned)kn * 7282u) >> 16;                                   \
      int r = kn - c * 9;                                                     \
      const int drow = (hs) * 32 + dl;                                        \
      const float vv[4] = {wreg[i].x, wreg[i].y, wreg[i].z, wreg[i].w};       \
      _Pragma("unroll")                                                       \
      for (int jx = 0; jx < 4; ++jx) {                                        \
        const int kp = r * 64 + c;                                            \
        const int slot = (kp >> 3) ^ (drow & 7);                              \
        Wl[buf][drow * KT + slot * 8 + (kp & 7)] = f2bf(vv[jx]);              \
        if (++r == 9) { r = 0; ++c; }                                         \
      }                                                                       \
    }                                                                         \
  }

#define MFMAS(jj, gg)                                                         \
  {                                                                           \
    _Pragma("unroll")                                                         \
    for (int s = 0; s < 3; ++s) {                                             \
      const int sb = ((gg) * 3 + s) * 4 + lg;                                 \
      const short8 b0 = *(const short8*)&Wl[(jj) & 1][wrow0 + ((sb ^ x7) << 3)]; \
      const short8 b1 = *(const short8*)&Wl[(jj) & 1][wrow1 + ((sb ^ x7) << 3)]; \
      acc[(jj)][0][0] = __builtin_amdgcn_mfma_f32_16x16x32_bf16(As0[((jj) * 6 + (gg)) % 3][s], b0, acc[(jj)][0][0], 0, 0, 0); \
      acc[(jj)][1][0] = __builtin_amdgcn_mfma_f32_16x16x32_bf16(As1[((jj) * 6 + (gg)) % 3][s], b0, acc[(jj)][1][0], 0, 0, 0); \
      acc[(jj)][0][1] = __builtin_amdgcn_mfma_f32_16x16x32_bf16(As0[((jj) * 6 + (gg)) % 3][s], b1, acc[(jj)][0][1], 0, 0, 0); \
      acc[(jj)][1][1] = __builtin_amdgcn_mfma_f32_16x16x32_bf16(As1[((jj) * 6 + (gg)) % 3][s], b1, acc[(jj)][1][1], 0, 0, 0); \
    }                                                                         \
  }

#define STEP(jj, gg, NN) { VMCNT(NN); SB(); MFMAS(jj, gg) }

  // one j-phase, j<3: W half-batches at phase start / after g3's drain
#define PHASE(jj)                                                             \
  ISSUE_W9(jj + 1, 0);                                                        \
  STEP(jj, 0, 21); ISSUE_A(6 * (jj) + 3);                                     \
  STEP(jj, 1, 21); ISSUE_A(6 * (jj) + 4);                                     \
  STEP(jj, 2, 21); ISSUE_A(6 * (jj) + 5);                                     \
  STEP(jj, 3, 12); SCATTER9((jj + 1) & 1, 0); ISSUE_W9(jj + 1, 1);            \
                   ISSUE_A(6 * (jj) + 6);                                     \
  STEP(jj, 4, 21); ISSUE_A(6 * (jj) + 7);                                     \
  STEP(jj, 5, 21); ISSUE_A(6 * (jj) + 8);                                     \
  VMCNT(18); SB(); SCATTER9((jj + 1) & 1, 1);                                 \
  __syncthreads(); SB();

  // ---- prologue (no vmcnt(0): A0 split around Wh1) ----
  ISSUE_W9(0, 0);
  ISSUE_A(0);
  VMCNT(6);  SB(); SCATTER9(0, 0);
  ISSUE_W9(0, 1);
  ISSUE_A(1); ISSUE_A(2);
  VMCNT(12); SB(); SCATTER9(0, 1);
  __syncthreads(); SB();

  PHASE(0)
  PHASE(1)
  PHASE(2)

  // ---- phase j=3 (no W prefetch) ----
  STEP(3, 0, 12); ISSUE_A(21);
  STEP(3, 1, 12); ISSUE_A(22);
  STEP(3, 2, 12); ISSUE_A(23);
  STEP(3, 3, 12);
  STEP(3, 4, 6);
  STEP(3, 5, 0);

  // ---- epilogue: float4 over the 4 consecutive w ----
#pragma unroll
  for (int dt = 0; dt < 2; ++dt) {
    const int dg = dh * 32 + dt * 16 + l15;
    const float bv0 = blds[dg], bv1 = blds[64 + dg], bv2 = blds[128 + dg], bv3 = blds[192 + dg];
#pragma unroll
    for (int bt = 0; bt < 2; ++bt) {
#pragma unroll
      for (int i = 0; i < 4; ++i) {
        const int b = bw * 32 + bt * 16 + lg * 4 + i;
        float4 v;
        v.x = acc[0][bt][dt][i] + bv0;
        v.y = acc[1][bt][dt][i] + bv1;
        v.z = acc[2][bt][dt][i] + bv2;
        v.w = acc[3][bt][dt][i] + bv3;
        *(float4*)(out + (size_t)b * 65536 + (size_t)dg * 1024 + h * 32 + wq * 4) = v;
      }
    }
  }
}

extern "C" void kernel_launch(void* const* d_in, const int* in_sizes, int n_in,
                              void* d_out, int out_size, void* d_ws, size_t ws_size,
                              hipStream_t stream) {
  const float* x    = (const float*)d_in[0];
  const float* wt   = (const float*)d_in[1];
  const float* bias = (const float*)d_in[2];
  float* out        = (float*)d_out;
  unsigned short* xC2 = (unsigned short*)d_ws;   // 18,939,904 B

  xC2_kernel<<<dim3(34, 8), 256, 0, stream>>>(x, xC2);
  lc_main<<<256, 512, 0, stream>>>(wt, bias, xC2, out);
}

// Round 16
// 62.755 us; speedup vs baseline: 3.1130x; 3.1130x over previous
//
#include <hip/hip_runtime.h>
#include <hip/hip_bf16.h>

#define KT 576   // CIN*9, GEMM k-order k' = (p*3+q)*64 + c

typedef __attribute__((ext_vector_type(8))) short  short8;
typedef __attribute__((ext_vector_type(4))) float  f32x4;

#define VMCNT(n) asm volatile("s_waitcnt vmcnt(" #n ")" ::: "memory")
#define SB() __builtin_amdgcn_sched_barrier(0)

__device__ __forceinline__ unsigned short f2bf(float f) {
  union { float f; unsigned int u; } v; v.f = f;
  return (unsigned short)((v.u + 0x7FFFu + ((v.u >> 16) & 1u)) >> 16);  // RNE
}

// ---------------------------------------------------------------------------
// Pre-pass: xC2 bf16, layout [hp 34][wp 34][bb 8][cs 8][bl 16][cl 8].
// ---------------------------------------------------------------------------
__global__ __launch_bounds__(256) void xC2_kernel(const float* __restrict__ x,
                                                  unsigned short* __restrict__ xC2) {
  const int hp = blockIdx.x, bb = blockIdx.y, t = threadIdx.x;
  __shared__ unsigned short tile[32 * 1024];   // [w 32][cs 8][bl 16][cl 8]
  const bool interior = (hp >= 1 && hp <= 32);
  if (interior) {
#pragma unroll 4
    for (int i = 0; i < 32; ++i) {
      const int row = i * 32 + (t >> 3);       // = bl*64 + c
      const int bl = row >> 6, c = row & 63;
      const int k = t & 7;
      const float4 v = *(const float4*)(x + ((size_t)(bb * 16 + bl) * 64 + c) * 1024 +
                                        (hp - 1) * 32 + k * 4);
      const int base = (k * 4) * 1024 + (c >> 3) * 128 + bl * 8 + (c & 7);
      tile[base]        = f2bf(v.x);
      tile[base + 1024] = f2bf(v.y);
      tile[base + 2048] = f2bf(v.z);
      tile[base + 3072] = f2bf(v.w);
    }
  }
  __syncthreads();
  unsigned short* dst = xC2 + (size_t)hp * 278528 + (size_t)bb * 1024;
  const uint4 z = make_uint4(0u, 0u, 0u, 0u);
  for (int idx = t; idx < 34 * 128; idx += 256) {
    const int wp = idx >> 7, s = idx & 127;
    uint4 v = z;
    if (interior && wp >= 1 && wp <= 32) v = *(const uint4*)&tile[(wp - 1) * 1024 + s * 8];
    *(uint4*)(dst + (size_t)wp * 8192 + s * 8) = v;
  }
}

// ---------------------------------------------------------------------------
// Main: 512 blocks = (h 32) x (wq 8) x (half 2); 256 thr (4 waves, b-tiles).
// A pipeline 2-deep (As[2][3]); W in 3 batches of 6 via one wreg[6].
// Counted-vmcnt ledger (in-order retirement walk, verified):
//   phase entry: [A(G0)..] arrived, [A(G0+1)] may be in flight (6).
//   g0 wait 6; other steps wait 12; W batches issued g0/g2/g4, each
//   scattered 2 steps later under VMCNT(12) (retires exactly that batch);
//   FINAL scatter waits VMCNT(6) (queue = [oldA, Wc, newA] -> retires
//   oldA+Wc; R15's VMCNT(12) left Wc in flight = the corruption bug).
// launch_bounds(256,1): no register cap -> no spills (the 128-cap diet
// cannot fit As48+wreg24+acc64=136 and spilled asm regs race, cf. R8).
// ---------------------------------------------------------------------------
__global__ __launch_bounds__(256, 1) void lc_main(const float* __restrict__ Wt,
                                                  const float* __restrict__ bias,
                                                  const unsigned short* __restrict__ xC2,
                                                  float* __restrict__ out) {
  __shared__ unsigned short Wl[2][32 * KT];   // 2 x 36864 B
  __shared__ float blds[128];                 // [j 4][dl 32]

  const int bid = (int)blockIdx.x;
  const int swz = (bid & 7) * 64 + (bid >> 3);    // 64-block chunks per XCD
  const int h = swz >> 4, rem = swz & 15, wq = rem >> 1, half = rem & 1;
  const int t = threadIdx.x, lane = t & 63, wv = t >> 6;
  const int l15 = lane & 15, lg = lane >> 4;

  if (t < 128)
    blds[t] = bias[(half * 32 + (t & 31)) * 1024 + h * 32 + wq * 4 + (t >> 5)];

  const unsigned short* xA = xC2 + (size_t)wv * 2048 + lg * 128 + l15 * 8;
  const int x7 = l15 & 7;
  const int wrow0 = l15 * KT;
  const int wrow1 = (16 + l15) * KT;

  f32x4 acc[4][2][2];
#pragma unroll
  for (int j = 0; j < 4; ++j)
#pragma unroll
    for (int bt = 0; bt < 2; ++bt)
#pragma unroll
      for (int dt = 0; dt < 2; ++dt) acc[j][bt][dt] = (f32x4){0.f, 0.f, 0.f, 0.f};

  short8 As0[2][3], As1[2][3];   // A slots [(j*6+g)%2][s]  (2-deep)
  float4 wreg[6];                // one W batch (6 x dwordx4), reused

#define ISSUE_W6(jj, bb)                                                      \
  {                                                                           \
    const float* ws = Wt + (size_t)(h * 32 + wq * 4 + (jj)) * (64 * KT) +     \
                      (size_t)half * (32 * KT);                               \
    _Pragma("unroll")                                                         \
    for (int i = 0; i < 6; ++i) {                                             \
      const float4* p = (const float4*)ws + (((bb) * 6 + i) * 256 + t);       \
      asm volatile("global_load_dwordx4 %0, %1, off" : "=v"(wreg[i]) : "v"(p)); \
    }                                                                         \
  }

#define ISSUE_A(K)                                                            \
  {                                                                           \
    _Pragma("unroll")                                                         \
    for (int s = 0; s < 3; ++s) {                                             \
      const int step = ((K) % 6) * 3 + s;                                     \
      const int pq = step >> 1, p = pq / 3, q = pq - p * 3;                   \
      const size_t off = (size_t)(h + p) * 278528 +                           \
                         (size_t)(wq * 4 + (K) / 6 + q) * 8192 + (step & 1) * 512; \
      const short8* p0 = (const short8*)(xA + off);                           \
      const short8* p1 = (const short8*)(xA + off + 1024);                    \
      asm volatile("global_load_dwordx4 %0, %1, off" : "=v"(As0[(K) % 2][s]) : "v"(p0)); \
      asm volatile("global_load_dwordx4 %0, %1, off" : "=v"(As1[(K) % 2][s]) : "v"(p1)); \
    }                                                                         \
  }

#define SCATTER6(buf, bb)                                                     \
  {                                                                           \
    _Pragma("unroll")                                                         \
    for (int i = 0; i < 6; ++i) {                                             \
      const int f = ((((bb) * 6) + i) * 256 + t) * 4;                         \
      const int d = (((unsigned)(f >> 6)) * 7282u) >> 16;                     \
      int kn = f - d * 576;                                                   \
      int c = ((unsigned)kn * 7282u) >> 16;                                   \
      int r = kn - c * 9;                                                     \
      const float vv[4] = {wreg[i].x, wreg[i].y, wreg[i].z, wreg[i].w};       \
      _Pragma("unroll")                                                       \
      for (int jx = 0; jx < 4; ++jx) {                                        \
        const int kp = r * 64 + c;                                            \
        const int slot = (kp >> 3) ^ (d & 7);                                 \
        Wl[buf][d * KT + slot * 8 + (kp & 7)] = f2bf(vv[jx]);                 \
        if (++r == 9) { r = 0; ++c; }                                         \
      }                                                                       \
    }                                                                         \
  }

#define MFMAS(jj, gg)                                                         \
  {                                                                           \
    _Pragma("unroll")                                                         \
    for (int s = 0; s < 3; ++s) {                                             \
      const int sb = ((gg) * 3 + s) * 4 + lg;                                 \
      const short8 b0 = *(const short8*)&Wl[(jj) & 1][wrow0 + ((sb ^ x7) << 3)]; \
      const short8 b1 = *(const short8*)&Wl[(jj) & 1][wrow1 + ((sb ^ x7) << 3)]; \
      acc[(jj)][0][0] = __builtin_amdgcn_mfma_f32_16x16x32_bf16(As0[((jj) * 6 + (gg)) % 2][s], b0, acc[(jj)][0][0], 0, 0, 0); \
      acc[(jj)][1][0] = __builtin_amdgcn_mfma_f32_16x16x32_bf16(As1[((jj) * 6 + (gg)) % 2][s], b0, acc[(jj)][1][0], 0, 0, 0); \
      acc[(jj)][0][1] = __builtin_amdgcn_mfma_f32_16x16x32_bf16(As0[((jj) * 6 + (gg)) % 2][s], b1, acc[(jj)][0][1], 0, 0, 0); \
      acc[(jj)][1][1] = __builtin_amdgcn_mfma_f32_16x16x32_bf16(As1[((jj) * 6 + (gg)) % 2][s], b1, acc[(jj)][1][1], 0, 0, 0); \
    }                                                                         \
  }

#define STEP(jj, gg, NN) { VMCNT(NN); SB(); MFMAS(jj, gg) }

  // steady phase jj<3; queue walk per step is annotated in the header comment
#define PHASE(jj)                                                             \
  STEP(jj, 0, 6);  ISSUE_A(6 * (jj) + 2); ISSUE_W6((jj) + 1, 0);              \
  STEP(jj, 1, 12); ISSUE_A(6 * (jj) + 3);                                     \
  STEP(jj, 2, 12); ISSUE_A(6 * (jj) + 4);                                     \
    VMCNT(12); SB(); SCATTER6(((jj) + 1) & 1, 0); ISSUE_W6((jj) + 1, 1);      \
  STEP(jj, 3, 12); ISSUE_A(6 * (jj) + 5);                                     \
  STEP(jj, 4, 12); ISSUE_A(6 * (jj) + 6);                                     \
    VMCNT(12); SB(); SCATTER6(((jj) + 1) & 1, 1); ISSUE_W6((jj) + 1, 2);      \
  STEP(jj, 5, 12); ISSUE_A(6 * (jj) + 7);                                     \
    VMCNT(6); SB(); SCATTER6(((jj) + 1) & 1, 2);                              \
  __syncthreads(); SB();

  // ---- prologue: W0 via 3 batches through wreg[6]; A(0),A(1) issued early ----
  ISSUE_W6(0, 0); ISSUE_A(0); ISSUE_A(1);
  VMCNT(12); SB(); SCATTER6(0, 0); ISSUE_W6(0, 1);
  VMCNT(0);  SB(); SCATTER6(0, 1); ISSUE_W6(0, 2);
  VMCNT(0);  SB(); SCATTER6(0, 2);
  __syncthreads(); SB();

  PHASE(0)
  PHASE(1)
  PHASE(2)

  // ---- phase j=3 (no W prefetch; A 2-deep tail) ----
  STEP(3, 0, 6);  ISSUE_A(20);
  STEP(3, 1, 6);  ISSUE_A(21);
  STEP(3, 2, 6);  ISSUE_A(22);
  STEP(3, 3, 6);  ISSUE_A(23);
  STEP(3, 4, 6);
  STEP(3, 5, 0);

  // ---- epilogue: float4 over the 4 consecutive w ----
#pragma unroll
  for (int dt = 0; dt < 2; ++dt) {
    const int dd = dt * 16 + l15;
    const int dg = half * 32 + dd;
    const float bv0 = blds[dd], bv1 = blds[32 + dd], bv2 = blds[64 + dd], bv3 = blds[96 + dd];
#pragma unroll
    for (int bt = 0; bt < 2; ++bt) {
#pragma unroll
      for (int i = 0; i < 4; ++i) {
        const int b = wv * 32 + bt * 16 + lg * 4 + i;
        float4 v;
        v.x = acc[0][bt][dt][i] + bv0;
        v.y = acc[1][bt][dt][i] + bv1;
        v.z = acc[2][bt][dt][i] + bv2;
        v.w = acc[3][bt][dt][i] + bv3;
        *(float4*)(out + (size_t)b * 65536 + (size_t)dg * 1024 + h * 32 + wq * 4) = v;
      }
    }
  }
}

extern "C" void kernel_launch(void* const* d_in, const int* in_sizes, int n_in,
                              void* d_out, int out_size, void* d_ws, size_t ws_size,
                              hipStream_t stream) {
  const float* x    = (const float*)d_in[0];
  const float* wt   = (const float*)d_in[1];
  const float* bias = (const float*)d_in[2];
  float* out        = (float*)d_out;
  unsigned short* xC2 = (unsigned short*)d_ws;   // 18,939,904 B

  xC2_kernel<<<dim3(34, 8), 256, 0, stream>>>(x, xC2);
  lc_main<<<512, 256, 0, stream>>>(wt, bias, xC2, out);
}

// Round 17
// 62.148 us; speedup vs baseline: 3.1434x; 1.0098x over previous
//
#include <hip/hip_runtime.h>
#include <hip/hip_bf16.h>

#define KT 576   // CIN*9, GEMM k-order k' = (p*3+q)*64 + c

typedef __attribute__((ext_vector_type(8))) short  short8;
typedef __attribute__((ext_vector_type(4))) float  f32x4;

#define VMCNT(n) asm volatile("s_waitcnt vmcnt(" #n ")" ::: "memory")
#define SB() __builtin_amdgcn_sched_barrier(0)

__device__ __forceinline__ unsigned short f2bf(float f) {
  union { float f; unsigned int u; } v; v.f = f;
  return (unsigned short)((v.u + 0x7FFFu + ((v.u >> 16) & 1u)) >> 16);  // RNE
}

// ---------------------------------------------------------------------------
// Pre-pass: xC2 bf16, layout [hp 34][wp 34][bb 8][cs 8][bl 16][cl 8].
// ---------------------------------------------------------------------------
__global__ __launch_bounds__(256) void xC2_kernel(const float* __restrict__ x,
                                                  unsigned short* __restrict__ xC2) {
  const int hp = blockIdx.x, bb = blockIdx.y, t = threadIdx.x;
  __shared__ unsigned short tile[32 * 1024];   // [w 32][cs 8][bl 16][cl 8]
  const bool interior = (hp >= 1 && hp <= 32);
  if (interior) {
#pragma unroll 4
    for (int i = 0; i < 32; ++i) {
      const int row = i * 32 + (t >> 3);       // = bl*64 + c
      const int bl = row >> 6, c = row & 63;
      const int k = t & 7;
      const float4 v = *(const float4*)(x + ((size_t)(bb * 16 + bl) * 64 + c) * 1024 +
                                        (hp - 1) * 32 + k * 4);
      const int base = (k * 4) * 1024 + (c >> 3) * 128 + bl * 8 + (c & 7);
      tile[base]        = f2bf(v.x);
      tile[base + 1024] = f2bf(v.y);
      tile[base + 2048] = f2bf(v.z);
      tile[base + 3072] = f2bf(v.w);
    }
  }
  __syncthreads();
  unsigned short* dst = xC2 + (size_t)hp * 278528 + (size_t)bb * 1024;
  const uint4 z = make_uint4(0u, 0u, 0u, 0u);
  for (int idx = t; idx < 34 * 128; idx += 256) {
    const int wp = idx >> 7, s = idx & 127;
    uint4 v = z;
    if (interior && wp >= 1 && wp <= 32) v = *(const uint4*)&tile[(wp - 1) * 1024 + s * 8];
    *(uint4*)(dst + (size_t)wp * 8192 + s * 8) = v;
  }
}

// ---------------------------------------------------------------------------
// Main: 512 blocks = (h 32) x (wq 8) x (half 2); 256 thr (4 waves, b-tiles).
// R16 structure (never-drain counted-vmcnt ledger, 2-deep A, wreg[6]) plus a
// bank-balanced slot mapping: group g=kp>>3 placed at sigma(g)=(g&7)*9+(g>>3)
// (^ d&7). Old mapping's bank-group = c>>3 (4 values/wave) -> ~4-way write
// conflicts (4.7M cycles); new = (c>>3 + r)%8 with r spanning 9 -> uniform.
// ---------------------------------------------------------------------------
__global__ __launch_bounds__(256, 1) void lc_main(const float* __restrict__ Wt,
                                                  const float* __restrict__ bias,
                                                  const unsigned short* __restrict__ xC2,
                                                  float* __restrict__ out) {
  __shared__ unsigned short Wl[2][32 * KT];   // 2 x 36864 B
  __shared__ float blds[128];                 // [j 4][dl 32]

  const int bid = (int)blockIdx.x;
  const int swz = (bid & 7) * 64 + (bid >> 3);    // 64-block chunks per XCD
  const int h = swz >> 4, rem = swz & 15, wq = rem >> 1, half = rem & 1;
  const int t = threadIdx.x, lane = t & 63, wv = t >> 6;
  const int l15 = lane & 15, lg = lane >> 4;

  if (t < 128)
    blds[t] = bias[(half * 32 + (t & 31)) * 1024 + h * 32 + wq * 4 + (t >> 5)];

  const unsigned short* xA = xC2 + (size_t)wv * 2048 + lg * 128 + l15 * 8;
  const int x7 = l15 & 7;
  const int wrow0 = l15 * KT;
  const int wrow1 = (16 + l15) * KT;

  f32x4 acc[4][2][2];
#pragma unroll
  for (int j = 0; j < 4; ++j)
#pragma unroll
    for (int bt = 0; bt < 2; ++bt)
#pragma unroll
      for (int dt = 0; dt < 2; ++dt) acc[j][bt][dt] = (f32x4){0.f, 0.f, 0.f, 0.f};

  short8 As0[2][3], As1[2][3];   // A slots [(j*6+g)%2][s]  (2-deep)
  float4 wreg[6];                // one W batch (6 x dwordx4), reused

#define ISSUE_W6(jj, bb)                                                      \
  {                                                                           \
    const float* ws = Wt + (size_t)(h * 32 + wq * 4 + (jj)) * (64 * KT) +     \
                      (size_t)half * (32 * KT);                               \
    _Pragma("unroll")                                                         \
    for (int i = 0; i < 6; ++i) {                                             \
      const float4* p = (const float4*)ws + (((bb) * 6 + i) * 256 + t);       \
      asm volatile("global_load_dwordx4 %0, %1, off" : "=v"(wreg[i]) : "v"(p)); \
    }                                                                         \
  }

#define ISSUE_A(K)                                                            \
  {                                                                           \
    _Pragma("unroll")                                                         \
    for (int s = 0; s < 3; ++s) {                                             \
      const int step = ((K) % 6) * 3 + s;                                     \
      const int pq = step >> 1, p = pq / 3, q = pq - p * 3;                   \
      const size_t off = (size_t)(h + p) * 278528 +                           \
                         (size_t)(wq * 4 + (K) / 6 + q) * 8192 + (step & 1) * 512; \
      const short8* p0 = (const short8*)(xA + off);                           \
      const short8* p1 = (const short8*)(xA + off + 1024);                    \
      asm volatile("global_load_dwordx4 %0, %1, off" : "=v"(As0[(K) % 2][s]) : "v"(p0)); \
      asm volatile("global_load_dwordx4 %0, %1, off" : "=v"(As1[(K) % 2][s]) : "v"(p1)); \
    }                                                                         \
  }

  // slot mapping: g = kp>>3 = r*8 + (c>>3); sigma = (g&7)*9 + (g>>3); ^ (d&7)
#define SCATTER6(buf, bb)                                                     \
  {                                                                           \
    _Pragma("unroll")                                                         \
    for (int i = 0; i < 6; ++i) {                                             \
      const int f = ((((bb) * 6) + i) * 256 + t) * 4;                         \
      const int d = (((unsigned)(f >> 6)) * 7282u) >> 16;                     \
      int kn = f - d * 576;                                                   \
      int c = ((unsigned)kn * 7282u) >> 16;                                   \
      int r = kn - c * 9;                                                     \
      const float vv[4] = {wreg[i].x, wreg[i].y, wreg[i].z, wreg[i].w};       \
      _Pragma("unroll")                                                       \
      for (int jx = 0; jx < 4; ++jx) {                                        \
        const int kp = r * 64 + c;                                            \
        const int sigma = ((c >> 3) * 9 + r);                                 \
        const int slot = sigma ^ (d & 7);                                     \
        Wl[buf][d * KT + slot * 8 + (kp & 7)] = f2bf(vv[jx]);                 \
        if (++r == 9) { r = 0; ++c; }                                         \
      }                                                                       \
    }                                                                         \
  }

#define MFMAS(jj, gg)                                                         \
  {                                                                           \
    _Pragma("unroll")                                                         \
    for (int s = 0; s < 3; ++s) {                                             \
      const int sb = ((gg) * 3 + s) * 4 + lg;                                 \
      const int sg = (sb & 7) * 9 + (sb >> 3);                                \
      const short8 b0 = *(const short8*)&Wl[(jj) & 1][wrow0 + ((sg ^ x7) << 3)]; \
      const short8 b1 = *(const short8*)&Wl[(jj) & 1][wrow1 + ((sg ^ x7) << 3)]; \
      acc[(jj)][0][0] = __builtin_amdgcn_mfma_f32_16x16x32_bf16(As0[((jj) * 6 + (gg)) % 2][s], b0, acc[(jj)][0][0], 0, 0, 0); \
      acc[(jj)][1][0] = __builtin_amdgcn_mfma_f32_16x16x32_bf16(As1[((jj) * 6 + (gg)) % 2][s], b0, acc[(jj)][1][0], 0, 0, 0); \
      acc[(jj)][0][1] = __builtin_amdgcn_mfma_f32_16x16x32_bf16(As0[((jj) * 6 + (gg)) % 2][s], b1, acc[(jj)][0][1], 0, 0, 0); \
      acc[(jj)][1][1] = __builtin_amdgcn_mfma_f32_16x16x32_bf16(As1[((jj) * 6 + (gg)) % 2][s], b1, acc[(jj)][1][1], 0, 0, 0); \
    }                                                                         \
  }

#define STEP(jj, gg, NN) { VMCNT(NN); SB(); MFMAS(jj, gg) }

  // steady phase jj<3 (R16-verified ledger; final scatter waits VMCNT(6))
#define PHASE(jj)                                                             \
  STEP(jj, 0, 6);  ISSUE_A(6 * (jj) + 2); ISSUE_W6((jj) + 1, 0);              \
  STEP(jj, 1, 12); ISSUE_A(6 * (jj) + 3);                                     \
  STEP(jj, 2, 12); ISSUE_A(6 * (jj) + 4);                                     \
    VMCNT(12); SB(); SCATTER6(((jj) + 1) & 1, 0); ISSUE_W6((jj) + 1, 1);      \
  STEP(jj, 3, 12); ISSUE_A(6 * (jj) + 5);                                     \
  STEP(jj, 4, 12); ISSUE_A(6 * (jj) + 6);                                     \
    VMCNT(12); SB(); SCATTER6(((jj) + 1) & 1, 1); ISSUE_W6((jj) + 1, 2);      \
  STEP(jj, 5, 12); ISSUE_A(6 * (jj) + 7);                                     \
    VMCNT(6); SB(); SCATTER6(((jj) + 1) & 1, 2);                              \
  __syncthreads(); SB();

  // ---- prologue: W0 via 3 batches through wreg[6]; A(0),A(1) issued early ----
  ISSUE_W6(0, 0); ISSUE_A(0); ISSUE_A(1);
  VMCNT(12); SB(); SCATTER6(0, 0); ISSUE_W6(0, 1);
  VMCNT(0);  SB(); SCATTER6(0, 1); ISSUE_W6(0, 2);
  VMCNT(0);  SB(); SCATTER6(0, 2);
  __syncthreads(); SB();

  PHASE(0)
  PHASE(1)
  PHASE(2)

  // ---- phase j=3 (no W prefetch; A 2-deep tail) ----
  STEP(3, 0, 6);  ISSUE_A(20);
  STEP(3, 1, 6);  ISSUE_A(21);
  STEP(3, 2, 6);  ISSUE_A(22);
  STEP(3, 3, 6);  ISSUE_A(23);
  STEP(3, 4, 6);
  STEP(3, 5, 0);

  // ---- epilogue: float4 over the 4 consecutive w ----
#pragma unroll
  for (int dt = 0; dt < 2; ++dt) {
    const int dd = dt * 16 + l15;
    const int dg = half * 32 + dd;
    const float bv0 = blds[dd], bv1 = blds[32 + dd], bv2 = blds[64 + dd], bv3 = blds[96 + dd];
#pragma unroll
    for (int bt = 0; bt < 2; ++bt) {
#pragma unroll
      for (int i = 0; i < 4; ++i) {
        const int b = wv * 32 + bt * 16 + lg * 4 + i;
        float4 v;
        v.x = acc[0][bt][dt][i] + bv0;
        v.y = acc[1][bt][dt][i] + bv1;
        v.z = acc[2][bt][dt][i] + bv2;
        v.w = acc[3][bt][dt][i] + bv3;
        *(float4*)(out + (size_t)b * 65536 + (size_t)dg * 1024 + h * 32 + wq * 4) = v;
      }
    }
  }
}

extern "C" void kernel_launch(void* const* d_in, const int* in_sizes, int n_in,
                              void* d_out, int out_size, void* d_ws, size_t ws_size,
                              hipStream_t stream) {
  const float* x    = (const float*)d_in[0];
  const float* wt   = (const float*)d_in[1];
  const float* bias = (const float*)d_in[2];
  float* out        = (float*)d_out;
  unsigned short* xC2 = (unsigned short*)d_ws;   // 18,939,904 B

  xC2_kernel<<<dim3(34, 8), 256, 0, stream>>>(x, xC2);
  lc_main<<<512, 256, 0, stream>>>(wt, bias, xC2, out);
}